// Round 1
// baseline (5567.168 us; speedup 1.0000x reference)
//
#include <hip/hip_runtime.h>
#include <math.h>

#define TT 50
#define BB 256
#define FF 96
#define HH 512
#define G3 1536
#define RNN_IN 288

typedef __attribute__((ext_vector_type(8))) short bhalf8;
typedef __attribute__((ext_vector_type(4))) float floatx4;

__device__ inline ushort f2bf(float f) {
    union { float f; unsigned u; } v; v.f = f;
    unsigned r = (v.u + 0x7FFFu + ((v.u >> 16) & 1u)) >> 16;
    return (ushort)r;
}
__device__ inline float bf2f(ushort h) {
    union { unsigned u; float f; } v; v.u = ((unsigned)h) << 16; return v.f;
}
__device__ inline bhalf8 ld8(const ushort* p) { return *(const bhalf8*)p; }
__device__ inline float sigmoidf_(float x) { return 1.f / (1.f + __expf(-x)); }

__device__ inline float pe_val(int pos, int d) {
    // div for column d uses exponent (d & ~1)
    float dv = expf(-9.210340371976184f * (float)(d & ~1) / 96.0f);
    float a = (float)pos * dv;
    return (d & 1) ? cosf(a) : sinf(a);
}

// ---------------- prep: weight cast fp32 -> bf16 ----------------
__global__ __launch_bounds__(256) void prep_weights(
    const float* Wih0, const float* Whh0, const float* Wih1, const float* Whh1, const float* Wlin,
    ushort* dWih0, ushort* dWhh0, ushort* dWih1, ushort* dWhh1, ushort* dWlin)
{
    const int n0 = G3 * RNN_IN;   // 442368
    const int n1 = G3 * HH;       // 786432
    const int n2 = FF * HH;       // 49152
    const int total = n0 + 3 * n1 + n2;
    for (int i = blockIdx.x * 256 + threadIdx.x; i < total; i += gridDim.x * 256) {
        int j = i;
        if (j < n0) { dWih0[j] = f2bf(Wih0[j]); continue; }
        j -= n0;
        if (j < n1) { dWhh0[j] = f2bf(Whh0[j]); continue; }
        j -= n1;
        if (j < n1) { dWih1[j] = f2bf(Wih1[j]); continue; }
        j -= n1;
        if (j < n1) { dWhh1[j] = f2bf(Whh1[j]); continue; }
        j -= n1;
        dWlin[j] = f2bf(Wlin[j]);
    }
}

// ---------------- prep: pe table, mask, x_en, h init, pred init ----------------
__global__ __launch_bounds__(256) void prep_misc(
    const float* __restrict__ input, float* pe, float* maskp, ushort* x_en,
    float* hf, ushort* hb, float* predf, ushort* predb)
{
    int i = blockIdx.x * 256 + threadIdx.x;
    // job 1: x_en (TT,BB,288) bf16
    if (i < TT * BB * RNN_IN) {
        int t = i / (BB * RNN_IN);
        int r = i % (BB * RNN_IN);
        int b = r / RNN_IN, c = r % RNN_IN;
        float v;
        if (c < FF) v = input[(t * BB + b) * FF + c];
        else if (c < 2 * FF) {
            int cc = c - FF;
            v = (t == 0) ? 0.f : input[(t * BB + b) * FF + cc] - input[((t - 1) * BB + b) * FF + cc];
        } else v = pe_val(t, c - 2 * FF);
        x_en[i] = f2bf(v);
        return;
    }
    i -= TT * BB * RNN_IN;
    // job 2: mask (B,F) + pred init
    if (i < BB * FF) {
        int b = i / FF, f = i % FF;
        float mean = 0.f, sq = 0.f;
        for (int t = 0; t < TT; t++) {
            float x = input[(t * BB + b) * FF + f];
            mean += x; sq += x * x;
        }
        mean /= (float)TT;
        float var = (sq - (float)TT * mean * mean) / (float)(TT - 1);
        float sd = sqrtf(fmaxf(var, 0.f));
        maskp[i] = (sd > 1e-4f) ? 1.f : 0.f;
        float p0 = input[i];          // input[0,b,f]
        predf[i] = p0;
        predb[i] = f2bf(p0);
        return;
    }
    i -= BB * FF;
    // job 3: pe table rows 0..99
    if (i < 100 * FF) { pe[i] = pe_val(i / FF, i % FF); return; }
    i -= 100 * FF;
    // job 4: zero h (fp32 4*131072 and bf16 4*131072)
    if (i < 4 * BB * HH) { hf[i] = 0.f; hb[i] = 0; return; }
}

// ---------------- Zpe: pe_dec part of decoder gi0 (+ b_ih0 folded) ----------------
__global__ __launch_bounds__(256) void zpe_kernel(
    const float* __restrict__ pe, const float* __restrict__ Wih0,
    const float* __restrict__ bih0, float* __restrict__ Zpe)
{
    int idx = blockIdx.x * 256 + threadIdx.x;
    if (idx >= TT * G3) return;
    int t = idx / G3, n = idx % G3;
    float s = bih0[n];
    const float* per = pe + (TT + t) * FF;
    const float* wr = Wih0 + n * RNN_IN + 2 * FF;
    for (int k = 0; k < FF; k++) s += per[k] * wr[k];
    Zpe[idx] = s;
}

// ---------------- Zvel0: vel part of decoder step-0 gi0 ----------------
__global__ __launch_bounds__(256) void zvel_kernel(
    const float* __restrict__ input, const float* __restrict__ Wih0, float* __restrict__ Zvel)
{
    int idx = blockIdx.x * 256 + threadIdx.x;
    if (idx >= BB * G3) return;
    int m = idx / G3, n = idx % G3;
    const float* a = input + m * FF;                     // input[0]
    const float* b = input + (TT - 1) * BB * FF + m * FF; // input[-1]
    const float* wr = Wih0 + n * RNN_IN + FF;
    float s = 0.f;
    for (int k = 0; k < FF; k++) s += (a[k] - b[k]) * wr[k];
    Zvel[idx] = s;
}

// ---------------- big GEMM: Z0 = bf16(x_en @ Wih0^T + b_ih0)  (12800x1536, K=288) ----------------
__global__ __launch_bounds__(256) void gemm_z0(
    const ushort* __restrict__ A, const ushort* __restrict__ W,
    const float* __restrict__ bias, ushort* __restrict__ C)
{
    int lane = threadIdx.x & 63, w = threadIdx.x >> 6;
    int row0 = blockIdx.x * 64 + w * 16;
    int c0 = blockIdx.y * 96;
    int l15 = lane & 15, q = lane >> 4;
    const ushort* ap = A + (row0 + l15) * RNN_IN + q * 8;
    floatx4 acc[6] = {};
    const ushort* wp[6];
#pragma unroll
    for (int j = 0; j < 6; j++) wp[j] = W + (c0 + 16 * j + l15) * RNN_IN + q * 8;
    for (int kt = 0; kt < RNN_IN / 32; kt++) {
        bhalf8 a = ld8(ap + kt * 32);
#pragma unroll
        for (int j = 0; j < 6; j++) {
            bhalf8 b = ld8(wp[j] + kt * 32);
            acc[j] = __builtin_amdgcn_mfma_f32_16x16x32_bf16(a, b, acc[j], 0, 0, 0);
        }
    }
#pragma unroll
    for (int j = 0; j < 6; j++) {
        int col = c0 + 16 * j + l15;
        float bb = bias[col];
#pragma unroll
        for (int i = 0; i < 4; i++) {
            int r = row0 + q * 4 + i;
            C[r * G3 + col] = f2bf(acc[j][i] + bb);
        }
    }
}

// ---------------- enc outputs: out = outs @ Wlin^T + b_lin + input (12800x96, K=512) ----------------
__global__ __launch_bounds__(256) void gemm_out_enc(
    const ushort* __restrict__ A, const ushort* __restrict__ W,
    const float* __restrict__ bias, const float* __restrict__ addsrc, float* __restrict__ out)
{
    int lane = threadIdx.x & 63, w = threadIdx.x >> 6;
    int row0 = blockIdx.x * 64 + w * 16;
    int l15 = lane & 15, q = lane >> 4;
    const ushort* ap = A + (row0 + l15) * HH + q * 8;
    floatx4 acc[6] = {};
    const ushort* wp[6];
#pragma unroll
    for (int j = 0; j < 6; j++) wp[j] = W + (16 * j + l15) * HH + q * 8;
    for (int kt = 0; kt < HH / 32; kt++) {
        bhalf8 a = ld8(ap + kt * 32);
#pragma unroll
        for (int j = 0; j < 6; j++) {
            bhalf8 b = ld8(wp[j] + kt * 32);
            acc[j] = __builtin_amdgcn_mfma_f32_16x16x32_bf16(a, b, acc[j], 0, 0, 0);
        }
    }
#pragma unroll
    for (int j = 0; j < 6; j++) {
        int col = 16 * j + l15;
        float bb = bias[col];
#pragma unroll
        for (int i = 0; i < 4; i++) {
            int r = row0 + q * 4 + i;
            out[r * FF + col] = acc[j][i] + bb + addsrc[r * FF + col];
        }
    }
}

// ---------------- decoder pred update: pred = (h1 @ Wlin^T + b_lin + pred) * mask ----------------
__global__ __launch_bounds__(256) void pred_step(
    const ushort* __restrict__ h1b, const ushort* __restrict__ W,
    const float* __restrict__ bias, const float* __restrict__ maskp,
    float* __restrict__ predf, ushort* __restrict__ predb, float* __restrict__ out_t)
{
    int lane = threadIdx.x & 63, w = threadIdx.x >> 6;
    int row0 = blockIdx.x * 64 + w * 16;
    int l15 = lane & 15, q = lane >> 4;
    const ushort* ap = h1b + (row0 + l15) * HH + q * 8;
    floatx4 acc[6] = {};
    const ushort* wp[6];
#pragma unroll
    for (int j = 0; j < 6; j++) wp[j] = W + (16 * j + l15) * HH + q * 8;
    for (int kt = 0; kt < HH / 32; kt++) {
        bhalf8 a = ld8(ap + kt * 32);
#pragma unroll
        for (int j = 0; j < 6; j++) {
            bhalf8 b = ld8(wp[j] + kt * 32);
            acc[j] = __builtin_amdgcn_mfma_f32_16x16x32_bf16(a, b, acc[j], 0, 0, 0);
        }
    }
#pragma unroll
    for (int j = 0; j < 6; j++) {
        int col = 16 * j + l15;
        float bb = bias[col];
#pragma unroll
        for (int i = 0; i < 4; i++) {
            int r = row0 + q * 4 + i;
            float v = acc[j][i] + bb + predf[r * FF + col];
            v *= maskp[r * FF + col];
            predf[r * FF + col] = v;
            predb[r * FF + col] = f2bf(v);
            out_t[r * FF + col] = v;
        }
    }
}

// ---------------- GRU layer step ----------------
// MODE 0: encoder layer0 (gi from precomputed Z0 slice, bf16)
// MODE 1: decoder layer0 (gi = pred @ Wih0[:, :96]^T + Zpe_t + optional Zvel)
// MODE 2: layer1        (gi = h0new @ Wih1^T + b_ih1)
template <int MODE>
__global__ __launch_bounds__(256) void gru_layer(
    const ushort* __restrict__ hprevb, const float* __restrict__ hprevf,
    float* __restrict__ hnewf, ushort* __restrict__ hnewb,
    const ushort* __restrict__ Whh, const float* __restrict__ bhh,
    const ushort* __restrict__ Zi, const ushort* __restrict__ Agi,
    const ushort* __restrict__ Wih, const float* __restrict__ bih,
    const float* __restrict__ Zpe_t, const float* __restrict__ Zvel,
    ushort* __restrict__ outs_t)
{
    int lane = threadIdx.x & 63, w = threadIdx.x >> 6;
    int row0 = blockIdx.x * 64 + w * 16;
    int c0 = blockIdx.y * 32;                  // h-column group
    int l15 = lane & 15, q = lane >> 4;

    // --- gh = hprev @ Whh^T ---
    floatx4 acch[6] = {};
    {
        const ushort* ap = hprevb + (row0 + l15) * HH + q * 8;
        const ushort* wp[6];
#pragma unroll
        for (int g = 0; g < 3; g++)
#pragma unroll
            for (int s = 0; s < 2; s++)
                wp[g * 2 + s] = Whh + (g * HH + c0 + 16 * s + l15) * HH + q * 8;
        for (int kt = 0; kt < HH / 32; kt++) {
            bhalf8 a = ld8(ap + kt * 32);
#pragma unroll
            for (int j = 0; j < 6; j++) {
                bhalf8 b = ld8(wp[j] + kt * 32);
                acch[j] = __builtin_amdgcn_mfma_f32_16x16x32_bf16(a, b, acch[j], 0, 0, 0);
            }
        }
    }

    // --- gi (MODE dependent) ---
    floatx4 acci[6] = {};
    if (MODE == 2) {
        const ushort* ap = Agi + (row0 + l15) * HH + q * 8;
        const ushort* wp[6];
#pragma unroll
        for (int g = 0; g < 3; g++)
#pragma unroll
            for (int s = 0; s < 2; s++)
                wp[g * 2 + s] = Wih + (g * HH + c0 + 16 * s + l15) * HH + q * 8;
        for (int kt = 0; kt < HH / 32; kt++) {
            bhalf8 a = ld8(ap + kt * 32);
#pragma unroll
            for (int j = 0; j < 6; j++) {
                bhalf8 b = ld8(wp[j] + kt * 32);
                acci[j] = __builtin_amdgcn_mfma_f32_16x16x32_bf16(a, b, acci[j], 0, 0, 0);
            }
        }
    } else if (MODE == 1) {
        const ushort* ap = Agi + (row0 + l15) * FF + q * 8;   // pred bf16 (B,96)
        const ushort* wp[6];
#pragma unroll
        for (int g = 0; g < 3; g++)
#pragma unroll
            for (int s = 0; s < 2; s++)
                wp[g * 2 + s] = Wih + (g * HH + c0 + 16 * s + l15) * RNN_IN + q * 8;
        for (int kt = 0; kt < FF / 32; kt++) {
            bhalf8 a = ld8(ap + kt * 32);
#pragma unroll
            for (int j = 0; j < 6; j++) {
                bhalf8 b = ld8(wp[j] + kt * 32);
                acci[j] = __builtin_amdgcn_mfma_f32_16x16x32_bf16(a, b, acci[j], 0, 0, 0);
            }
        }
    }

    // --- gates + h update ---
#pragma unroll
    for (int s = 0; s < 2; s++) {
        int col = c0 + 16 * s + l15;
        float bh_r = bhh[col], bh_z = bhh[HH + col], bh_n = bhh[2 * HH + col];
#pragma unroll
        for (int i = 0; i < 4; i++) {
            int r = row0 + q * 4 + i;
            float gh_r = acch[s][i] + bh_r;
            float gh_z = acch[2 + s][i] + bh_z;
            float gh_n = acch[4 + s][i] + bh_n;
            float gi_r, gi_z, gi_n;
            if (MODE == 0) {
                const ushort* zr = Zi + r * G3;
                gi_r = bf2f(zr[col]); gi_z = bf2f(zr[HH + col]); gi_n = bf2f(zr[2 * HH + col]);
            } else if (MODE == 1) {
                gi_r = acci[s][i] + Zpe_t[col];
                gi_z = acci[2 + s][i] + Zpe_t[HH + col];
                gi_n = acci[4 + s][i] + Zpe_t[2 * HH + col];
                if (Zvel) {
                    const float* zv = Zvel + r * G3;
                    gi_r += zv[col]; gi_z += zv[HH + col]; gi_n += zv[2 * HH + col];
                }
            } else {
                gi_r = acci[s][i] + bih[col];
                gi_z = acci[2 + s][i] + bih[HH + col];
                gi_n = acci[4 + s][i] + bih[2 * HH + col];
            }
            float rg = sigmoidf_(gi_r + gh_r);
            float zg = sigmoidf_(gi_z + gh_z);
            float ng = tanhf(gi_n + rg * gh_n);
            float hold = hprevf[r * HH + col];
            float hn = (1.f - zg) * ng + zg * hold;
            hnewf[r * HH + col] = hn;
            ushort hv = f2bf(hn);
            hnewb[r * HH + col] = hv;
            if (MODE == 2 && outs_t) outs_t[r * HH + col] = hv;
        }
    }
}

// ================= host =================
extern "C" void kernel_launch(void* const* d_in, const int* in_sizes, int n_in,
                              void* d_out, int out_size, void* d_ws, size_t ws_size,
                              hipStream_t stream)
{
    const float* input = (const float*)d_in[0];
    const float* W_ih0 = (const float*)d_in[1];
    const float* W_hh0 = (const float*)d_in[2];
    const float* b_ih0 = (const float*)d_in[3];
    const float* b_hh0 = (const float*)d_in[4];
    const float* W_ih1 = (const float*)d_in[5];
    const float* W_hh1 = (const float*)d_in[6];
    const float* b_ih1 = (const float*)d_in[7];
    const float* b_hh1 = (const float*)d_in[8];
    const float* W_lin = (const float*)d_in[9];
    const float* b_lin = (const float*)d_in[10];
    float* out = (float*)d_out;

    char* ws = (char*)d_ws;
    size_t off = 0;
    auto alloc = [&](size_t bytes) -> char* {
        off = (off + 255) & ~(size_t)255;
        char* p = ws + off;
        off += bytes;
        return p;
    };

    ushort* Wih0b = (ushort*)alloc((size_t)G3 * RNN_IN * 2);
    ushort* Whh0b = (ushort*)alloc((size_t)G3 * HH * 2);
    ushort* Wih1b = (ushort*)alloc((size_t)G3 * HH * 2);
    ushort* Whh1b = (ushort*)alloc((size_t)G3 * HH * 2);
    ushort* Wlinb = (ushort*)alloc((size_t)FF * HH * 2);
    ushort* x_en  = (ushort*)alloc((size_t)TT * BB * RNN_IN * 2);
    ushort* Z0    = (ushort*)alloc((size_t)TT * BB * G3 * 2);
    ushort* outs  = (ushort*)alloc((size_t)TT * BB * HH * 2);
    float*  Zpe   = (float*)alloc((size_t)TT * G3 * 4);
    float*  Zvel  = (float*)alloc((size_t)BB * G3 * 4);
    float*  pe    = (float*)alloc((size_t)100 * FF * 4);
    float*  maskp = (float*)alloc((size_t)BB * FF * 4);
    float*  hf    = (float*)alloc((size_t)4 * BB * HH * 4);   // h0f[2], h1f[2]
    ushort* hb    = (ushort*)alloc((size_t)4 * BB * HH * 2);
    float*  predf = (float*)alloc((size_t)BB * FF * 4);
    ushort* predb = (ushort*)alloc((size_t)BB * FF * 2);
    (void)ws_size; (void)in_sizes; (void)n_in; (void)out_size;

    const int HS = BB * HH; // 131072
    auto h0f = [&](int p) { return hf + p * HS; };
    auto h1f = [&](int p) { return hf + 2 * HS + p * HS; };
    auto h0b = [&](int p) { return hb + p * HS; };
    auto h1b = [&](int p) { return hb + 2 * HS + p * HS; };

    dim3 blk(256);

    prep_weights<<<dim3(512), blk, 0, stream>>>(W_ih0, W_hh0, W_ih1, W_hh1, W_lin,
                                                Wih0b, Whh0b, Wih1b, Whh1b, Wlinb);

    {
        int total = TT * BB * RNN_IN + BB * FF + 100 * FF + 4 * BB * HH;
        prep_misc<<<dim3((total + 255) / 256), blk, 0, stream>>>(
            input, pe, maskp, x_en, hf, hb, predf, predb);
    }

    gemm_z0<<<dim3(TT * BB / 64, G3 / 96), blk, 0, stream>>>(x_en, Wih0b, b_ih0, Z0);
    zpe_kernel<<<dim3((TT * G3 + 255) / 256), blk, 0, stream>>>(pe, W_ih0, b_ih0, Zpe);
    zvel_kernel<<<dim3((BB * G3 + 255) / 256), blk, 0, stream>>>(input, W_ih0, Zvel);

    dim3 ggrid(BB / 64, HH / 32);

    // ---- encoder ----
    for (int t = 0; t < TT; t++) {
        int s = t;
        int p = s & 1, np = 1 - p;
        gru_layer<0><<<ggrid, blk, 0, stream>>>(
            h0b(p), h0f(p), h0f(np), h0b(np), Whh0b, b_hh0,
            Z0 + (size_t)t * BB * G3, nullptr, nullptr, nullptr, nullptr, nullptr, nullptr);
        gru_layer<2><<<ggrid, blk, 0, stream>>>(
            h1b(p), h1f(p), h1f(np), h1b(np), Whh1b, b_hh1,
            nullptr, h0b(np), Wih1b, b_ih1, nullptr, nullptr, outs + (size_t)t * BB * HH);
    }

    gemm_out_enc<<<dim3(TT * BB / 64, 1), blk, 0, stream>>>(outs, Wlinb, b_lin, input, out);

    // ---- decoder ----
    for (int t = 0; t < TT; t++) {
        int s = TT + t;
        int p = s & 1, np = 1 - p;
        gru_layer<1><<<ggrid, blk, 0, stream>>>(
            h0b(p), h0f(p), h0f(np), h0b(np), Whh0b, b_hh0,
            nullptr, predb, Wih0b, nullptr, Zpe + (size_t)t * G3,
            (t == 0) ? Zvel : nullptr, nullptr);
        gru_layer<2><<<ggrid, blk, 0, stream>>>(
            h1b(p), h1f(p), h1f(np), h1b(np), Whh1b, b_hh1,
            nullptr, h0b(np), Wih1b, b_ih1, nullptr, nullptr, nullptr);
        pred_step<<<dim3(BB / 64), blk, 0, stream>>>(
            h1b(np), Wlinb, b_lin, maskp, predf, predb,
            out + (size_t)TT * BB * FF + (size_t)t * BB * FF);
    }
}

// Round 3
// 5073.601 us; speedup vs baseline: 1.0973x; 1.0973x over previous
//
#include <hip/hip_runtime.h>
#include <math.h>

#define TT 50
#define BB 256
#define FF 96
#define HH 512
#define G3 1536
#define RNN_IN 288
#define NB 128

typedef __attribute__((ext_vector_type(8))) short bhalf8;
typedef __attribute__((ext_vector_type(4))) float floatx4;
#define MFMA16 __builtin_amdgcn_mfma_f32_16x16x32_bf16

__device__ inline ushort f2bf(float f) {
    union { float f; unsigned u; } v; v.f = f;
    unsigned r = (v.u + 0x7FFFu + ((v.u >> 16) & 1u)) >> 16;
    return (ushort)r;
}
__device__ inline float bf2f(ushort h) {
    union { unsigned u; float f; } v; v.u = ((unsigned)h) << 16; return v.f;
}
__device__ inline bhalf8 ld8(const ushort* p) { return *(const bhalf8*)p; }
__device__ inline float sigmoidf_(float x) { return 1.f / (1.f + __expf(-x)); }

__device__ inline float pe_val(int pos, int d) {
    float dv = expf(-9.210340371976184f * (float)(d & ~1) / 96.0f);
    float a = (float)pos * dv;
    return (d & 1) ? cosf(a) : sinf(a);
}

// ---------------- prep: weight cast fp32 -> bf16 ----------------
__global__ __launch_bounds__(256) void prep_weights(
    const float* Wih0, const float* Whh0, const float* Wih1, const float* Whh1, const float* Wlin,
    ushort* dWih0, ushort* dWhh0, ushort* dWih1, ushort* dWhh1, ushort* dWlin)
{
    const int n0 = G3 * RNN_IN;
    const int n1 = G3 * HH;
    const int n2 = FF * HH;
    const int total = n0 + 3 * n1 + n2;
    for (int i = blockIdx.x * 256 + threadIdx.x; i < total; i += gridDim.x * 256) {
        int j = i;
        if (j < n0) { dWih0[j] = f2bf(Wih0[j]); continue; }
        j -= n0;
        if (j < n1) { dWhh0[j] = f2bf(Whh0[j]); continue; }
        j -= n1;
        if (j < n1) { dWih1[j] = f2bf(Wih1[j]); continue; }
        j -= n1;
        if (j < n1) { dWhh1[j] = f2bf(Whh1[j]); continue; }
        j -= n1;
        dWlin[j] = f2bf(Wlin[j]);
    }
}

// ---------------- prep: pe, mask, x_en, h init, pred init, barrier zero ----------------
__global__ __launch_bounds__(256) void prep_misc(
    const float* __restrict__ input, float* pe, float* maskp, ushort* x_en,
    float* hf, ushort* hb, float* predf, ushort* predb, unsigned* bar)
{
    int i = blockIdx.x * 256 + threadIdx.x;
    if (i < TT * BB * RNN_IN) {
        int t = i / (BB * RNN_IN);
        int r = i % (BB * RNN_IN);
        int b = r / RNN_IN, c = r % RNN_IN;
        float v;
        if (c < FF) v = input[(t * BB + b) * FF + c];
        else if (c < 2 * FF) {
            int cc = c - FF;
            v = (t == 0) ? 0.f : input[(t * BB + b) * FF + cc] - input[((t - 1) * BB + b) * FF + cc];
        } else v = pe_val(t, c - 2 * FF);
        x_en[i] = f2bf(v);
        return;
    }
    i -= TT * BB * RNN_IN;
    if (i < BB * FF) {
        int b = i / FF, f = i % FF;
        float mean = 0.f, sq = 0.f;
        for (int t = 0; t < TT; t++) {
            float x = input[(t * BB + b) * FF + f];
            mean += x; sq += x * x;
        }
        mean /= (float)TT;
        float var = (sq - (float)TT * mean * mean) / (float)(TT - 1);
        float sd = sqrtf(fmaxf(var, 0.f));
        maskp[i] = (sd > 1e-4f) ? 1.f : 0.f;
        float p0 = input[i];
        predf[i] = p0;
        predb[i] = f2bf(p0);
        return;
    }
    i -= BB * FF;
    if (i < 100 * FF) { pe[i] = pe_val(i / FF, i % FF); return; }
    i -= 100 * FF;
    if (i < 4 * BB * HH) { hf[i] = 0.f; hb[i] = 0; return; }
    i -= 4 * BB * HH;
    if (i < 1024) { bar[i] = 0; return; }
}

// ---------------- Zpe: pe_dec part of decoder gi0 (+ b_ih0 folded) ----------------
__global__ __launch_bounds__(256) void zpe_kernel(
    const float* __restrict__ pe, const float* __restrict__ Wih0,
    const float* __restrict__ bih0, float* __restrict__ Zpe)
{
    int idx = blockIdx.x * 256 + threadIdx.x;
    if (idx >= TT * G3) return;
    int t = idx / G3, n = idx % G3;
    float s = bih0[n];
    const float* per = pe + (TT + t) * FF;
    const float* wr = Wih0 + n * RNN_IN + 2 * FF;
    for (int k = 0; k < FF; k++) s += per[k] * wr[k];
    Zpe[idx] = s;
}

// ---------------- Zvel0: vel part of decoder step-0 gi0 ----------------
__global__ __launch_bounds__(256) void zvel_kernel(
    const float* __restrict__ input, const float* __restrict__ Wih0, float* __restrict__ Zvel)
{
    int idx = blockIdx.x * 256 + threadIdx.x;
    if (idx >= BB * G3) return;
    int m = idx / G3, n = idx % G3;
    const float* a = input + m * FF;
    const float* b = input + (TT - 1) * BB * FF + m * FF;
    const float* wr = Wih0 + n * RNN_IN + FF;
    float s = 0.f;
    for (int k = 0; k < FF; k++) s += (a[k] - b[k]) * wr[k];
    Zvel[idx] = s;
}

// ---------------- big GEMM: Z0 = bf16(x_en @ Wih0^T + b_ih0) ----------------
__global__ __launch_bounds__(256) void gemm_z0(
    const ushort* __restrict__ A, const ushort* __restrict__ W,
    const float* __restrict__ bias, ushort* __restrict__ C)
{
    int lane = threadIdx.x & 63, w = threadIdx.x >> 6;
    int row0 = blockIdx.x * 64 + w * 16;
    int c0 = blockIdx.y * 96;
    int l15 = lane & 15, q = lane >> 4;
    const ushort* ap = A + (size_t)(row0 + l15) * RNN_IN + q * 8;
    floatx4 acc[6] = {};
    const ushort* wp[6];
#pragma unroll
    for (int j = 0; j < 6; j++) wp[j] = W + (size_t)(c0 + 16 * j + l15) * RNN_IN + q * 8;
    for (int kt = 0; kt < RNN_IN / 32; kt++) {
        bhalf8 a = ld8(ap + kt * 32);
#pragma unroll
        for (int j = 0; j < 6; j++) {
            bhalf8 b = ld8(wp[j] + kt * 32);
            acc[j] = MFMA16(a, b, acc[j], 0, 0, 0);
        }
    }
#pragma unroll
    for (int j = 0; j < 6; j++) {
        int col = c0 + 16 * j + l15;
        float bb = bias[col];
#pragma unroll
        for (int i = 0; i < 4; i++) {
            int r = row0 + q * 4 + i;
            C[(size_t)r * G3 + col] = f2bf(acc[j][i] + bb);
        }
    }
}

// ---------------- enc outputs: out = outs @ Wlin^T + b_lin + input ----------------
__global__ __launch_bounds__(256) void gemm_out_enc(
    const ushort* __restrict__ A, const ushort* __restrict__ W,
    const float* __restrict__ bias, const float* __restrict__ addsrc, float* __restrict__ out)
{
    int lane = threadIdx.x & 63, w = threadIdx.x >> 6;
    int row0 = blockIdx.x * 64 + w * 16;
    int l15 = lane & 15, q = lane >> 4;
    const ushort* ap = A + (size_t)(row0 + l15) * HH + q * 8;
    floatx4 acc[6] = {};
    const ushort* wp[6];
#pragma unroll
    for (int j = 0; j < 6; j++) wp[j] = W + (size_t)(16 * j + l15) * HH + q * 8;
    for (int kt = 0; kt < HH / 32; kt++) {
        bhalf8 a = ld8(ap + kt * 32);
#pragma unroll
        for (int j = 0; j < 6; j++) {
            bhalf8 b = ld8(wp[j] + kt * 32);
            acc[j] = MFMA16(a, b, acc[j], 0, 0, 0);
        }
    }
#pragma unroll
    for (int j = 0; j < 6; j++) {
        int col = 16 * j + l15;
        float bb = bias[col];
#pragma unroll
        for (int i = 0; i < 4; i++) {
            int r = row0 + q * 4 + i;
            out[(size_t)r * FF + col] = acc[j][i] + bb + addsrc[(size_t)r * FF + col];
        }
    }
}

// ================= persistent cooperative kernel =================

struct PArgs {
    const ushort* Z0;
    const ushort* Wih0b; const ushort* Whh0b;
    const ushort* Wih1b; const ushort* Whh1b; const ushort* Wlinb;
    const float* bhh0; const float* bih1; const float* bhh1; const float* blin;
    const float* Zpe; const float* Zvel; const float* maskp;
    float* hf; ushort* hb;
    float* predf; ushort* predb;
    ushort* outs; float* out;
    unsigned* bar;   // [grp*32] counters for 16 groups, [512] global cnt, [513] gen
};

// two-level grid barrier: 16 groups of 8 blocks
__device__ inline void gbar(unsigned* bar, unsigned target) {
    __syncthreads();
    if (threadIdx.x == 0) {
        unsigned* gc = bar + ((blockIdx.x >> 3) << 5);
        unsigned prev = __hip_atomic_fetch_add(gc, 1u, __ATOMIC_ACQ_REL, __HIP_MEMORY_SCOPE_AGENT);
        if (prev == 7u) {
            __hip_atomic_store(gc, 0u, __ATOMIC_RELAXED, __HIP_MEMORY_SCOPE_AGENT);
            unsigned p2 = __hip_atomic_fetch_add(bar + 512, 1u, __ATOMIC_ACQ_REL, __HIP_MEMORY_SCOPE_AGENT);
            if (p2 == 15u) {
                __hip_atomic_store(bar + 512, 0u, __ATOMIC_RELAXED, __HIP_MEMORY_SCOPE_AGENT);
                __hip_atomic_store(bar + 513, target, __ATOMIC_RELEASE, __HIP_MEMORY_SCOPE_AGENT);
            }
        }
        while (__hip_atomic_load(bar + 513, __ATOMIC_RELAXED, __HIP_MEMORY_SCOPE_AGENT) < target) {
            __builtin_amdgcn_s_sleep(1);
        }
        __builtin_amdgcn_fence(__ATOMIC_ACQUIRE, "agent");
    }
    __syncthreads();
}

// 3-gate GEMM: acc[g] += A[16 rows x K] * W[gate g rows c0..c0+15, K]^T
__device__ inline void gemm3_acc(const ushort* __restrict__ A, int lda,
                                 const ushort* __restrict__ W, int ldw,
                                 int nKt, floatx4 acc[3],
                                 int arow, int c0, int l15, int q)
{
    const ushort* ap = A + (size_t)(arow + l15) * lda + q * 8;
    const ushort* w0 = W + (size_t)(0 * HH + c0 + l15) * ldw + q * 8;
    const ushort* w1 = W + (size_t)(1 * HH + c0 + l15) * ldw + q * 8;
    const ushort* w2 = W + (size_t)(2 * HH + c0 + l15) * ldw + q * 8;
    for (int kt = 0; kt < nKt; kt++) {
        bhalf8 a = ld8(ap); ap += 32;
        acc[0] = MFMA16(a, ld8(w0), acc[0], 0, 0, 0); w0 += 32;
        acc[1] = MFMA16(a, ld8(w1), acc[1], 0, 0, 0); w1 += 32;
        acc[2] = MFMA16(a, ld8(w2), acc[2], 0, 0, 0); w2 += 32;
    }
}

__device__ inline void gru_write(const floatx4 gi[3], const floatx4 gh[3],
    const float* __restrict__ bhh, const float* __restrict__ hprevf,
    float* __restrict__ hnewf, ushort* __restrict__ hnewb,
    ushort* __restrict__ outs_t, int row0, int col, int q)
{
    float bh_r = bhh[col], bh_z = bhh[HH + col], bh_n = bhh[2 * HH + col];
#pragma unroll
    for (int i = 0; i < 4; i++) {
        int r = row0 + q * 4 + i;
        float rg = sigmoidf_(gi[0][i] + gh[0][i] + bh_r);
        float zg = sigmoidf_(gi[1][i] + gh[1][i] + bh_z);
        float ng = tanhf(gi[2][i] + rg * (gh[2][i] + bh_n));
        float hn = (1.f - zg) * ng + zg * hprevf[(size_t)r * HH + col];
        hnewf[(size_t)r * HH + col] = hn;
        ushort hv = f2bf(hn);
        hnewb[(size_t)r * HH + col] = hv;
        if (outs_t) outs_t[(size_t)r * HH + col] = hv;
    }
}

__global__ __launch_bounds__(256) void persistent_kernel(PArgs P)
{
    const int lane = threadIdx.x & 63, w = threadIdx.x >> 6;
    const int l15 = lane & 15, q = lane >> 4;
    const int bc = blockIdx.x & 31, br = blockIdx.x >> 5;
    const int row0 = br * 64 + w * 16;
    const int c0 = bc * 16;
    const int col = c0 + l15;
    const int HS = BB * HH;
    float* hf = P.hf; ushort* hb = P.hb;
    unsigned tgt = 0;

    // ---- encoder: epoch s runs A(s) [layer0] and B(s-1) [layer1], 1 barrier each ----
    for (int s = 0; s <= TT; s++) {
        if (s < TT) {
            int pp = s & 1;
            floatx4 gh[3] = {};
            gemm3_acc(hb + pp * HS, HH, P.Whh0b, HH, HH / 32, gh, row0, c0, l15, q);
            floatx4 gi[3];
            const ushort* Z0t = P.Z0 + (size_t)s * BB * G3;
#pragma unroll
            for (int g = 0; g < 3; g++)
#pragma unroll
                for (int i = 0; i < 4; i++)
                    gi[g][i] = bf2f(Z0t[(size_t)(row0 + q * 4 + i) * G3 + g * HH + col]);
            gru_write(gi, gh, P.bhh0, hf + pp * HS, hf + (1 - pp) * HS, hb + (1 - pp) * HS,
                      nullptr, row0, col, q);
        }
        if (s > 0) {
            int t = s - 1, pp = t & 1;
            floatx4 gh[3] = {}, gi[3] = {};
            gemm3_acc(hb + (1 - pp) * HS, HH, P.Wih1b, HH, HH / 32, gi, row0, c0, l15, q);
            gemm3_acc(hb + 2 * HS + pp * HS, HH, P.Whh1b, HH, HH / 32, gh, row0, c0, l15, q);
#pragma unroll
            for (int g = 0; g < 3; g++) {
                float bi = P.bih1[g * HH + col];
#pragma unroll
                for (int i = 0; i < 4; i++) gi[g][i] += bi;
            }
            gru_write(gi, gh, P.bhh1, hf + 2 * HS + pp * HS, hf + 2 * HS + (1 - pp) * HS,
                      hb + 2 * HS + (1 - pp) * HS, P.outs + (size_t)t * BB * HH, row0, col, q);
        }
        gbar(P.bar, ++tgt);
    }

    // ---- decoder: A / B / C phases, 3 barriers per step ----
    for (int t = 0; t < TT; t++) {
        int pp = t & 1;  // (50+t)&1 == t&1
        // A: layer0 from pred
        {
            floatx4 gh[3] = {}, gi[3] = {};
            gemm3_acc(hb + pp * HS, HH, P.Whh0b, HH, HH / 32, gh, row0, c0, l15, q);
            gemm3_acc(P.predb, FF, P.Wih0b, RNN_IN, FF / 32, gi, row0, c0, l15, q);
            const float* zp = P.Zpe + (size_t)t * G3;
#pragma unroll
            for (int g = 0; g < 3; g++) {
                float zz = zp[g * HH + col];
#pragma unroll
                for (int i = 0; i < 4; i++) {
                    gi[g][i] += zz;
                    if (t == 0) gi[g][i] += P.Zvel[(size_t)(row0 + q * 4 + i) * G3 + g * HH + col];
                }
            }
            gru_write(gi, gh, P.bhh0, hf + pp * HS, hf + (1 - pp) * HS, hb + (1 - pp) * HS,
                      nullptr, row0, col, q);
        }
        gbar(P.bar, ++tgt);
        // B: layer1
        {
            floatx4 gh[3] = {}, gi[3] = {};
            gemm3_acc(hb + (1 - pp) * HS, HH, P.Wih1b, HH, HH / 32, gi, row0, c0, l15, q);
            gemm3_acc(hb + 2 * HS + pp * HS, HH, P.Whh1b, HH, HH / 32, gh, row0, c0, l15, q);
#pragma unroll
            for (int g = 0; g < 3; g++) {
                float bi = P.bih1[g * HH + col];
#pragma unroll
                for (int i = 0; i < 4; i++) gi[g][i] += bi;
            }
            gru_write(gi, gh, P.bhh1, hf + 2 * HS + pp * HS, hf + 2 * HS + (1 - pp) * HS,
                      hb + 2 * HS + (1 - pp) * HS, nullptr, row0, col, q);
        }
        gbar(P.bar, ++tgt);
        // C: pred update (96 wave-jobs on blocks 0..23)
        if (blockIdx.x < 24) {
            int job = blockIdx.x * 4 + w;      // 0..95
            int rt = job / 6, ct = job % 6;
            const ushort* ap = hb + 2 * HS + (1 - pp) * HS + (size_t)(rt * 16 + l15) * HH + q * 8;
            const ushort* wp = P.Wlinb + (size_t)(ct * 16 + l15) * HH + q * 8;
            floatx4 acc = {};
            for (int kt = 0; kt < HH / 32; kt++) {
                acc = MFMA16(ld8(ap), ld8(wp), acc, 0, 0, 0);
                ap += 32; wp += 32;
            }
            int pcol = ct * 16 + l15;
            float bl = P.blin[pcol];
            float* outt = P.out + (size_t)(TT + t) * BB * FF;
#pragma unroll
            for (int i = 0; i < 4; i++) {
                int r = rt * 16 + q * 4 + i;
                float v = acc[i] + bl + P.predf[r * FF + pcol];
                v *= P.maskp[r * FF + pcol];
                P.predf[r * FF + pcol] = v;
                P.predb[r * FF + pcol] = f2bf(v);
                outt[r * FF + pcol] = v;
            }
        }
        if (t < TT - 1) gbar(P.bar, ++tgt);
    }
}

// ================= host =================
extern "C" void kernel_launch(void* const* d_in, const int* in_sizes, int n_in,
                              void* d_out, int out_size, void* d_ws, size_t ws_size,
                              hipStream_t stream)
{
    const float* input = (const float*)d_in[0];
    const float* W_ih0 = (const float*)d_in[1];
    const float* W_hh0 = (const float*)d_in[2];
    const float* b_ih0 = (const float*)d_in[3];
    const float* b_hh0 = (const float*)d_in[4];
    const float* W_ih1 = (const float*)d_in[5];
    const float* W_hh1 = (const float*)d_in[6];
    const float* b_ih1 = (const float*)d_in[7];
    const float* b_hh1 = (const float*)d_in[8];
    const float* W_lin = (const float*)d_in[9];
    const float* b_lin = (const float*)d_in[10];
    float* out = (float*)d_out;

    char* ws = (char*)d_ws;
    size_t off = 0;
    auto alloc = [&](size_t bytes) -> char* {
        off = (off + 255) & ~(size_t)255;
        char* p = ws + off;
        off += bytes;
        return p;
    };

    ushort* Wih0b = (ushort*)alloc((size_t)G3 * RNN_IN * 2);
    ushort* Whh0b = (ushort*)alloc((size_t)G3 * HH * 2);
    ushort* Wih1b = (ushort*)alloc((size_t)G3 * HH * 2);
    ushort* Whh1b = (ushort*)alloc((size_t)G3 * HH * 2);
    ushort* Wlinb = (ushort*)alloc((size_t)FF * HH * 2);
    ushort* x_en  = (ushort*)alloc((size_t)TT * BB * RNN_IN * 2);
    ushort* Z0    = (ushort*)alloc((size_t)TT * BB * G3 * 2);
    ushort* outs  = (ushort*)alloc((size_t)TT * BB * HH * 2);
    float*  Zpe   = (float*)alloc((size_t)TT * G3 * 4);
    float*  Zvel  = (float*)alloc((size_t)BB * G3 * 4);
    float*  pe    = (float*)alloc((size_t)100 * FF * 4);
    float*  maskp = (float*)alloc((size_t)BB * FF * 4);
    float*  hf    = (float*)alloc((size_t)4 * BB * HH * 4);
    ushort* hb    = (ushort*)alloc((size_t)4 * BB * HH * 2);
    float*  predf = (float*)alloc((size_t)BB * FF * 4);
    ushort* predb = (ushort*)alloc((size_t)BB * FF * 2);
    unsigned* bar = (unsigned*)alloc(1024 * 4);
    (void)ws_size; (void)in_sizes; (void)n_in; (void)out_size;

    dim3 blk(256);

    prep_weights<<<dim3(512), blk, 0, stream>>>(W_ih0, W_hh0, W_ih1, W_hh1, W_lin,
                                                Wih0b, Whh0b, Wih1b, Whh1b, Wlinb);
    {
        int total = TT * BB * RNN_IN + BB * FF + 100 * FF + 4 * BB * HH + 1024;
        prep_misc<<<dim3((total + 255) / 256), blk, 0, stream>>>(
            input, pe, maskp, x_en, hf, hb, predf, predb, bar);
    }
    gemm_z0<<<dim3(TT * BB / 64, G3 / 96), blk, 0, stream>>>(x_en, Wih0b, b_ih0, Z0);
    zpe_kernel<<<dim3((TT * G3 + 255) / 256), blk, 0, stream>>>(pe, W_ih0, b_ih0, Zpe);
    zvel_kernel<<<dim3((BB * G3 + 255) / 256), blk, 0, stream>>>(input, W_ih0, Zvel);

    PArgs P;
    P.Z0 = Z0; P.Wih0b = Wih0b; P.Whh0b = Whh0b; P.Wih1b = Wih1b; P.Whh1b = Whh1b; P.Wlinb = Wlinb;
    P.bhh0 = b_hh0; P.bih1 = b_ih1; P.bhh1 = b_hh1; P.blin = b_lin;
    P.Zpe = Zpe; P.Zvel = Zvel; P.maskp = maskp;
    P.hf = hf; P.hb = hb; P.predf = predf; P.predb = predb;
    P.outs = outs; P.out = out; P.bar = bar;

    void* kargs[] = { &P };
    hipError_t e = hipLaunchCooperativeKernel((void*)persistent_kernel, dim3(NB), dim3(256), kargs, 0, stream);
    (void)e;

    gemm_out_enc<<<dim3(TT * BB / 64, 1), blk, 0, stream>>>(outs, Wlinb, b_lin, input, out);
}

// Round 4
// 3837.598 us; speedup vs baseline: 1.4507x; 1.3221x over previous
//
#include <hip/hip_runtime.h>
#include <math.h>

#define TT 50
#define BB 256
#define FF 96
#define HH 512
#define G3 1536
#define RNN_IN 288
#define HSZ (BB * HH)

typedef __attribute__((ext_vector_type(8))) short bhalf8;
typedef __attribute__((ext_vector_type(4))) float floatx4;
#define MFMA16 __builtin_amdgcn_mfma_f32_16x16x32_bf16

__device__ inline ushort f2bf(float f) {
    union { float f; unsigned u; } v; v.f = f;
    unsigned r = (v.u + 0x7FFFu + ((v.u >> 16) & 1u)) >> 16;
    return (ushort)r;
}
__device__ inline float bf2f(ushort h) {
    union { unsigned u; float f; } v; v.u = ((unsigned)h) << 16; return v.f;
}
__device__ inline bhalf8 ld8(const ushort* p) { return *(const bhalf8*)p; }
__device__ inline float sigmoidf_(float x) { return 1.f / (1.f + __expf(-x)); }

__device__ inline float pe_val(int pos, int d) {
    float dv = expf(-9.210340371976184f * (float)(d & ~1) / 96.0f);
    float a = (float)pos * dv;
    return (d & 1) ? cosf(a) : sinf(a);
}

// coherent (agent-scope, L2-bypassing) 16B load of 8 bf16
__device__ inline bhalf8 ald16(const ushort* p) {
    union { unsigned long long u[2]; bhalf8 v; } x;
    x.u[0] = __hip_atomic_load((const unsigned long long*)p, __ATOMIC_RELAXED, __HIP_MEMORY_SCOPE_AGENT);
    x.u[1] = __hip_atomic_load((const unsigned long long*)(p + 4), __ATOMIC_RELAXED, __HIP_MEMORY_SCOPE_AGENT);
    return x.v;
}

// ---------------- prep: weight cast fp32 -> bf16 ----------------
__global__ __launch_bounds__(256) void prep_weights(
    const float* Wih0, const float* Whh0, const float* Wih1, const float* Whh1, const float* Wlin,
    ushort* dWih0, ushort* dWhh0, ushort* dWih1, ushort* dWhh1, ushort* dWlin)
{
    const int n0 = G3 * RNN_IN;
    const int n1 = G3 * HH;
    const int n2 = FF * HH;
    const int total = n0 + 3 * n1 + n2;
    for (int i = blockIdx.x * 256 + threadIdx.x; i < total; i += gridDim.x * 256) {
        int j = i;
        if (j < n0) { dWih0[j] = f2bf(Wih0[j]); continue; }
        j -= n0;
        if (j < n1) { dWhh0[j] = f2bf(Whh0[j]); continue; }
        j -= n1;
        if (j < n1) { dWih1[j] = f2bf(Wih1[j]); continue; }
        j -= n1;
        if (j < n1) { dWhh1[j] = f2bf(Whh1[j]); continue; }
        j -= n1;
        dWlin[j] = f2bf(Wlin[j]);
    }
}

// ---------------- prep: pe, mask, x_en, h init, slots zero ----------------
__global__ __launch_bounds__(256) void prep_misc(
    const float* __restrict__ input, float* pe, float* maskp, ushort* x_en,
    ushort* hb, unsigned* bar)
{
    int i = blockIdx.x * 256 + threadIdx.x;
    if (i < TT * BB * RNN_IN) {
        int t = i / (BB * RNN_IN);
        int r = i % (BB * RNN_IN);
        int b = r / RNN_IN, c = r % RNN_IN;
        float v;
        if (c < FF) v = input[(t * BB + b) * FF + c];
        else if (c < 2 * FF) {
            int cc = c - FF;
            v = (t == 0) ? 0.f : input[(t * BB + b) * FF + cc] - input[((t - 1) * BB + b) * FF + cc];
        } else v = pe_val(t, c - 2 * FF);
        x_en[i] = f2bf(v);
        return;
    }
    i -= TT * BB * RNN_IN;
    if (i < BB * FF) {
        int b = i / FF, f = i % FF;
        float mean = 0.f, sq = 0.f;
        for (int t = 0; t < TT; t++) {
            float x = input[(t * BB + b) * FF + f];
            mean += x; sq += x * x;
        }
        mean /= (float)TT;
        float var = (sq - (float)TT * mean * mean) / (float)(TT - 1);
        float sd = sqrtf(fmaxf(var, 0.f));
        maskp[i] = (sd > 1e-4f) ? 1.f : 0.f;
        return;
    }
    i -= BB * FF;
    if (i < 100 * FF) { pe[i] = pe_val(i / FF, i % FF); return; }
    i -= 100 * FF;
    if (i < 4 * BB * HH) { hb[i] = 0; return; }   // h0buf[2] + h1buf[2]
    i -= 4 * BB * HH;
    if (i < 1024) { bar[i] = 0; return; }
}

// ---------------- Zpe: pe_dec part of decoder gi0 (+ b_ih0 folded) ----------------
__global__ __launch_bounds__(256) void zpe_kernel(
    const float* __restrict__ pe, const float* __restrict__ Wih0,
    const float* __restrict__ bih0, float* __restrict__ Zpe)
{
    int idx = blockIdx.x * 256 + threadIdx.x;
    if (idx >= TT * G3) return;
    int t = idx / G3, n = idx % G3;
    float s = bih0[n];
    const float* per = pe + (TT + t) * FF;
    const float* wr = Wih0 + n * RNN_IN + 2 * FF;
    for (int k = 0; k < FF; k++) s += per[k] * wr[k];
    Zpe[idx] = s;
}

// ---------------- Zvel0: input[0] + vel parts of decoder step-0 gi0 ----------------
__global__ __launch_bounds__(256) void zvel_kernel(
    const float* __restrict__ input, const float* __restrict__ Wih0, float* __restrict__ Zvel)
{
    int idx = blockIdx.x * 256 + threadIdx.x;
    if (idx >= BB * G3) return;
    int m = idx / G3, n = idx % G3;
    const float* a0 = input + m * FF;                       // input[0]
    const float* aL = input + (TT - 1) * BB * FF + m * FF;  // input[-1]
    const float* wr = Wih0 + n * RNN_IN;
    float s = 0.f;
    for (int k = 0; k < FF; k++) s += a0[k] * wr[k] + (a0[k] - aL[k]) * wr[FF + k];
    Zvel[idx] = s;
}

// ---------------- big GEMM: Z0T[t][gatecol][b] = bf16(x_en @ Wih0^T + b_ih0) ----------------
__global__ __launch_bounds__(256) void gemm_z0t(
    const ushort* __restrict__ A, const ushort* __restrict__ W,
    const float* __restrict__ bias, ushort* __restrict__ C)
{
    int lane = threadIdx.x & 63, w = threadIdx.x >> 6;
    int row0 = blockIdx.x * 64 + w * 16;
    int c0 = blockIdx.y * 96;
    int l15 = lane & 15, q = lane >> 4;
    const ushort* ap = A + (size_t)(row0 + l15) * RNN_IN + q * 8;
    floatx4 acc[6] = {};
    const ushort* wp[6];
#pragma unroll
    for (int j = 0; j < 6; j++) wp[j] = W + (size_t)(c0 + 16 * j + l15) * RNN_IN + q * 8;
    for (int kt = 0; kt < RNN_IN / 32; kt++) {
        bhalf8 a = ld8(ap + kt * 32);
#pragma unroll
        for (int j = 0; j < 6; j++) {
            bhalf8 b = ld8(wp[j] + kt * 32);
            acc[j] = MFMA16(a, b, acc[j], 0, 0, 0);
        }
    }
    int gr = row0 + q * 4;           // 4 consecutive global rows
    int t = gr / BB, b = gr % BB;
#pragma unroll
    for (int j = 0; j < 6; j++) {
        int col = c0 + 16 * j + l15;
        float bb = bias[col];
#pragma unroll
        for (int i = 0; i < 4; i++)
            C[(size_t)t * G3 * BB + (size_t)col * BB + b + i] = f2bf(acc[j][i] + bb);
    }
}

// ---------------- enc outputs: out = outs @ Wlin^T + b_lin + input ----------------
__global__ __launch_bounds__(256) void gemm_out_enc(
    const ushort* __restrict__ A, const ushort* __restrict__ W,
    const float* __restrict__ bias, const float* __restrict__ addsrc, float* __restrict__ out)
{
    int lane = threadIdx.x & 63, w = threadIdx.x >> 6;
    int row0 = blockIdx.x * 64 + w * 16;
    int l15 = lane & 15, q = lane >> 4;
    const ushort* ap = A + (size_t)(row0 + l15) * HH + q * 8;
    floatx4 acc[6] = {};
    const ushort* wp[6];
#pragma unroll
    for (int j = 0; j < 6; j++) wp[j] = W + (size_t)(16 * j + l15) * HH + q * 8;
    for (int kt = 0; kt < HH / 32; kt++) {
        bhalf8 a = ld8(ap + kt * 32);
#pragma unroll
        for (int j = 0; j < 6; j++) {
            bhalf8 b = ld8(wp[j] + kt * 32);
            acc[j] = MFMA16(a, b, acc[j], 0, 0, 0);
        }
    }
#pragma unroll
    for (int j = 0; j < 6; j++) {
        int col = 16 * j + l15;
        float bb = bias[col];
#pragma unroll
        for (int i = 0; i < 4; i++) {
            int r = row0 + q * 4 + i;
            out[(size_t)r * FF + col] = acc[j][i] + bb + addsrc[(size_t)r * FF + col];
        }
    }
}

// ================= persistent cooperative kernel =================
// 256 blocks x 128 threads. block = (rg = bid>>4) row-group of 16 rows,
// (cg = bid&15) col-group of 32 h-cols (2 waves x 16). Sync only among the
// 16 col-partners of a row-group. fp32 recurrence state lives in LDS.
// h (bf16) crosses blocks via agent-scope relaxed atomics (no cache fences,
// weights stay L2-resident).

struct PArgs {
    const ushort* Z0T;        // [TT][G3][BB]
    const ushort* Wih0b;      // [G3][288]
    const ushort* Whh0b; const ushort* Wih1b; const ushort* Whh1b;  // [G3][512]
    const ushort* Wlinb;      // [96][512]
    const float* bhh0; const float* bih1; const float* bhh1; const float* blin;
    const float* Zpe;         // [TT][G3]  (pe part + b_ih0)
    const float* Zvel;        // [BB][G3]  (input0 + vel parts, dec t=0)
    const float* maskp;       // [BB][96]
    const float* input;       // input[0] for pred init
    ushort* h0buf;            // [2][BB][HH]
    ushort* h1buf;            // [2][BB][HH]
    ushort* outs;             // [TT][BB][HH]
    float* out;
    unsigned* slots;          // [16 rg][16 cg]
};

__global__ __launch_bounds__(128) void persistent2(PArgs P)
{
    const int tid = threadIdx.x;
    const int w = tid >> 6;
    const int lane = tid & 63;
    const int l15 = lane & 15, q = lane >> 4;
    const int rg = blockIdx.x >> 4, cg = blockIdx.x & 15;
    const int row0 = rg * 16;
    const int ct16 = cg * 32 + w * 16;
    const int hcol = ct16 + l15;

    __shared__ float h0f[16][32];
    __shared__ float h1f[16][32];
    __shared__ float predf[16][96];
    __shared__ float maskl[16][96];
    __shared__ ushort predb[16][104];

    for (int i = tid; i < 16 * 32; i += 128) { ((float*)h0f)[i] = 0.f; ((float*)h1f)[i] = 0.f; }
    for (int i = tid; i < 16 * 96; i += 128) {
        int r = i / 96, c = i % 96;
        float p0 = P.input[(row0 + r) * FF + c];
        predf[r][c] = p0;
        predb[r][c] = f2bf(p0);
        maskl[r][c] = P.maskp[(row0 + r) * FF + c];
    }
    __syncthreads();

    unsigned phase = 0;
    unsigned* slots = P.slots + rg * 16;

    auto rsync = [&]() {
        phase++;
        asm volatile("s_waitcnt vmcnt(0)" ::: "memory");
        __syncthreads();
        if (tid == 0)
            __hip_atomic_store(&slots[cg], phase, __ATOMIC_RELEASE, __HIP_MEMORY_SCOPE_AGENT);
        if (tid < 16) {
            while (__hip_atomic_load(&slots[tid], __ATOMIC_RELAXED, __HIP_MEMORY_SCOPE_AGENT) < phase)
                __builtin_amdgcn_s_sleep(1);
        }
        __syncthreads();
        asm volatile("" ::: "memory");
    };

    // 3-gate GEMM, A from coherent global h, W from L2-cached weights
    auto gemm3_glob = [&](const ushort* Ab, const ushort* W, floatx4 acc[3]) {
        const ushort* ap = Ab + (size_t)(row0 + l15) * HH + q * 8;
        const ushort* w0 = W + (size_t)(0 * HH + ct16 + l15) * HH + q * 8;
        const ushort* w1 = W + (size_t)(1 * HH + ct16 + l15) * HH + q * 8;
        const ushort* w2 = W + (size_t)(2 * HH + ct16 + l15) * HH + q * 8;
        for (int kt = 0; kt < 16; kt++) {
            bhalf8 a = ald16(ap); ap += 32;
            acc[0] = MFMA16(a, ld8(w0), acc[0], 0, 0, 0); w0 += 32;
            acc[1] = MFMA16(a, ld8(w1), acc[1], 0, 0, 0); w1 += 32;
            acc[2] = MFMA16(a, ld8(w2), acc[2], 0, 0, 0); w2 += 32;
        }
    };

    auto gru_epi = [&](const floatx4 gi[3], const floatx4 gh[3], const float* bhh,
                       float (*hfl)[32], ushort* hnb, ushort* outs_t) {
        float bh_r = bhh[hcol], bh_z = bhh[HH + hcol], bh_n = bhh[2 * HH + hcol];
        int cidx = w * 16 + l15;
#pragma unroll
        for (int i = 0; i < 4; i++) {
            int r = q * 4 + i;
            float rg_ = sigmoidf_(gi[0][i] + gh[0][i] + bh_r);
            float zg = sigmoidf_(gi[1][i] + gh[1][i] + bh_z);
            float ng = tanhf(gi[2][i] + rg_ * (gh[2][i] + bh_n));
            float hn = (1.f - zg) * ng + zg * hfl[r][cidx];
            hfl[r][cidx] = hn;
            ushort hv = f2bf(hn);
            __hip_atomic_store(hnb + (size_t)(row0 + r) * HH + hcol, hv,
                               __ATOMIC_RELAXED, __HIP_MEMORY_SCOPE_AGENT);
            if (outs_t) outs_t[(size_t)(row0 + r) * HH + hcol] = hv;
        }
    };

    // ---- encoder: phase s runs L0(s) and L1(s-1); 1 sync per phase ----
    for (int s = 0; s <= TT; s++) {
        if (s < TT) {
            int pp = s & 1;
            floatx4 gh[3] = {};
            gemm3_glob(P.h0buf + pp * HSZ, P.Whh0b, gh);
            floatx4 gi[3];
            const ushort* zt = P.Z0T + (size_t)s * G3 * BB;
#pragma unroll
            for (int g = 0; g < 3; g++) {
                union { unsigned long long u; ushort s4[4]; } z;
                z.u = *(const unsigned long long*)(zt + (size_t)(g * HH + hcol) * BB + row0 + q * 4);
#pragma unroll
                for (int i = 0; i < 4; i++) gi[g][i] = bf2f(z.s4[i]);
            }
            gru_epi(gi, gh, P.bhh0, h0f, P.h0buf + (1 - pp) * HSZ, nullptr);
        }
        if (s > 0) {
            int t = s - 1, pp = t & 1;
            floatx4 gi[3] = {}, gh[3] = {};
            gemm3_glob(P.h0buf + (1 - pp) * HSZ, P.Wih1b, gi);
            gemm3_glob(P.h1buf + pp * HSZ, P.Whh1b, gh);
#pragma unroll
            for (int g = 0; g < 3; g++) {
                float bi = P.bih1[g * HH + hcol];
#pragma unroll
                for (int i = 0; i < 4; i++) gi[g][i] += bi;
            }
            gru_epi(gi, gh, P.bhh1, h1f, P.h1buf + (1 - pp) * HSZ, P.outs + (size_t)t * BB * HH);
        }
        rsync();
    }

    // ---- decoder: 2 phases per step ----
    auto pred_part = [&](int tpred, int bufsel) {
        // pred(tpred) from h1(tpred) in h1buf[bufsel]; all 16 col-partners compute full 96 cols
        const ushort* h1p = P.h1buf + bufsel * HSZ;
        floatx4 pa[3] = {};
        const ushort* ap = h1p + (size_t)(row0 + l15) * HH + q * 8;
        const ushort* wl0 = P.Wlinb + (size_t)((0 * 2 + w) * 16 + l15) * HH + q * 8;
        const ushort* wl1 = P.Wlinb + (size_t)((1 * 2 + w) * 16 + l15) * HH + q * 8;
        const ushort* wl2 = P.Wlinb + (size_t)((2 * 2 + w) * 16 + l15) * HH + q * 8;
        for (int kt = 0; kt < 16; kt++) {
            bhalf8 a = ald16(ap); ap += 32;
            pa[0] = MFMA16(a, ld8(wl0), pa[0], 0, 0, 0); wl0 += 32;
            pa[1] = MFMA16(a, ld8(wl1), pa[1], 0, 0, 0); wl1 += 32;
            pa[2] = MFMA16(a, ld8(wl2), pa[2], 0, 0, 0); wl2 += 32;
        }
        float* outt = P.out + (size_t)(TT + tpred) * BB * FF;
#pragma unroll
        for (int j = 0; j < 3; j++) {
            int fc = (j * 2 + w) * 16 + l15;
            float bl = P.blin[fc];
#pragma unroll
            for (int i = 0; i < 4; i++) {
                int r = q * 4 + i;
                float v = pa[j][i] + bl + predf[r][fc];
                v *= maskl[r][fc];
                predf[r][fc] = v;
                predb[r][fc] = f2bf(v);
                if (cg == 0) outt[(size_t)(row0 + r) * FF + fc] = v;
            }
        }
    };

    for (int t = 0; t < TT; t++) {
        int pp = t & 1;
        // P2: pred(t-1) (redundant per block) + L0(t)
        if (t > 0) {
            pred_part(t - 1, pp);   // h1(t-1) lives in buf[t&1]
            __syncthreads();        // predb ready for L0 gi
        }
        {
            floatx4 gh[3] = {};
            gemm3_glob(P.h0buf + pp * HSZ, P.Whh0b, gh);
            floatx4 gi[3] = {};
            if (t == 0) {
#pragma unroll
                for (int g = 0; g < 3; g++)
#pragma unroll
                    for (int i = 0; i < 4; i++)
                        gi[g][i] = P.Zvel[(size_t)(row0 + q * 4 + i) * G3 + g * HH + hcol];
            } else {
                const ushort* w0 = P.Wih0b + (size_t)(0 * HH + ct16 + l15) * RNN_IN + q * 8;
                const ushort* w1 = P.Wih0b + (size_t)(1 * HH + ct16 + l15) * RNN_IN + q * 8;
                const ushort* w2 = P.Wih0b + (size_t)(2 * HH + ct16 + l15) * RNN_IN + q * 8;
                for (int kt = 0; kt < 3; kt++) {
                    bhalf8 a = *(const bhalf8*)(&predb[l15][kt * 32 + q * 8]);
                    gi[0] = MFMA16(a, ld8(w0), gi[0], 0, 0, 0); w0 += 32;
                    gi[1] = MFMA16(a, ld8(w1), gi[1], 0, 0, 0); w1 += 32;
                    gi[2] = MFMA16(a, ld8(w2), gi[2], 0, 0, 0); w2 += 32;
                }
            }
            const float* zp = P.Zpe + (size_t)t * G3;
#pragma unroll
            for (int g = 0; g < 3; g++) {
                float zz = zp[g * HH + hcol];
#pragma unroll
                for (int i = 0; i < 4; i++) gi[g][i] += zz;
            }
            gru_epi(gi, gh, P.bhh0, h0f, P.h0buf + (1 - pp) * HSZ, nullptr);
        }
        rsync();
        // P1: L1(t)
        {
            floatx4 gi[3] = {}, gh[3] = {};
            gemm3_glob(P.h0buf + (1 - pp) * HSZ, P.Wih1b, gi);
            gemm3_glob(P.h1buf + pp * HSZ, P.Whh1b, gh);
#pragma unroll
            for (int g = 0; g < 3; g++) {
                float bi = P.bih1[g * HH + hcol];
#pragma unroll
                for (int i = 0; i < 4; i++) gi[g][i] += bi;
            }
            gru_epi(gi, gh, P.bhh1, h1f, P.h1buf + (1 - pp) * HSZ, nullptr);
        }
        rsync();
    }
    // tail: pred(49); h1(49) in buf[(49+1)&1] = buf[0]
    pred_part(TT - 1, 0);
}

// ================= host =================
extern "C" void kernel_launch(void* const* d_in, const int* in_sizes, int n_in,
                              void* d_out, int out_size, void* d_ws, size_t ws_size,
                              hipStream_t stream)
{
    const float* input = (const float*)d_in[0];
    const float* W_ih0 = (const float*)d_in[1];
    const float* W_hh0 = (const float*)d_in[2];
    const float* b_ih0 = (const float*)d_in[3];
    const float* b_hh0 = (const float*)d_in[4];
    const float* W_ih1 = (const float*)d_in[5];
    const float* W_hh1 = (const float*)d_in[6];
    const float* b_ih1 = (const float*)d_in[7];
    const float* b_hh1 = (const float*)d_in[8];
    const float* W_lin = (const float*)d_in[9];
    const float* b_lin = (const float*)d_in[10];
    float* out = (float*)d_out;

    char* ws = (char*)d_ws;
    size_t off = 0;
    auto alloc = [&](size_t bytes) -> char* {
        off = (off + 255) & ~(size_t)255;
        char* p = ws + off;
        off += bytes;
        return p;
    };

    ushort* Wih0b = (ushort*)alloc((size_t)G3 * RNN_IN * 2);
    ushort* Whh0b = (ushort*)alloc((size_t)G3 * HH * 2);
    ushort* Wih1b = (ushort*)alloc((size_t)G3 * HH * 2);
    ushort* Whh1b = (ushort*)alloc((size_t)G3 * HH * 2);
    ushort* Wlinb = (ushort*)alloc((size_t)FF * HH * 2);
    ushort* x_en  = (ushort*)alloc((size_t)TT * BB * RNN_IN * 2);
    ushort* Z0T   = (ushort*)alloc((size_t)TT * BB * G3 * 2);
    ushort* outs  = (ushort*)alloc((size_t)TT * BB * HH * 2);
    float*  Zpe   = (float*)alloc((size_t)TT * G3 * 4);
    float*  Zvel  = (float*)alloc((size_t)BB * G3 * 4);
    float*  pe    = (float*)alloc((size_t)100 * FF * 4);
    float*  maskp = (float*)alloc((size_t)BB * FF * 4);
    ushort* hb    = (ushort*)alloc((size_t)4 * BB * HH * 2);   // h0buf[2] + h1buf[2]
    unsigned* bar = (unsigned*)alloc(1024 * 4);
    (void)ws_size; (void)in_sizes; (void)n_in; (void)out_size;

    dim3 blk(256);

    prep_weights<<<dim3(512), blk, 0, stream>>>(W_ih0, W_hh0, W_ih1, W_hh1, W_lin,
                                                Wih0b, Whh0b, Wih1b, Whh1b, Wlinb);
    {
        int total = TT * BB * RNN_IN + BB * FF + 100 * FF + 4 * BB * HH + 1024;
        prep_misc<<<dim3((total + 255) / 256), blk, 0, stream>>>(
            input, pe, maskp, x_en, hb, bar);
    }
    gemm_z0t<<<dim3(TT * BB / 64, G3 / 96), blk, 0, stream>>>(x_en, Wih0b, b_ih0, Z0T);
    zpe_kernel<<<dim3((TT * G3 + 255) / 256), blk, 0, stream>>>(pe, W_ih0, b_ih0, Zpe);
    zvel_kernel<<<dim3((BB * G3 + 255) / 256), blk, 0, stream>>>(input, W_ih0, Zvel);

    PArgs P;
    P.Z0T = Z0T; P.Wih0b = Wih0b; P.Whh0b = Whh0b; P.Wih1b = Wih1b; P.Whh1b = Whh1b; P.Wlinb = Wlinb;
    P.bhh0 = b_hh0; P.bih1 = b_ih1; P.bhh1 = b_hh1; P.blin = b_lin;
    P.Zpe = Zpe; P.Zvel = Zvel; P.maskp = maskp; P.input = input;
    P.h0buf = hb; P.h1buf = hb + 2 * HSZ;
    P.outs = outs; P.out = out; P.slots = bar;

    void* kargs[] = { &P };
    hipError_t e = hipLaunchCooperativeKernel((void*)persistent2, dim3(256), dim3(128), kargs, 0, stream);
    (void)e;

    gemm_out_enc<<<dim3(TT * BB / 64, 1), blk, 0, stream>>>(outs, Wlinb, b_lin, input, out);
}